// Round 1
// baseline (702.366 us; speedup 1.0000x reference)
//
#include <hip/hip_runtime.h>

#define B_ 4
#define T_ 2048
#define C_ 2048
#define H_ 16
#define N1_ 6144
#define M_ 8192
#define SCALE_ 0.08838834764831845f

typedef unsigned short u16;
typedef __bf16 bf16x8 __attribute__((ext_vector_type(8)));
typedef float f32x4 __attribute__((ext_vector_type(4)));

__device__ __forceinline__ u16 f2bf(float f) {
  union { float f; unsigned u; } v; v.f = f;
  return (u16)((v.u + 0x7fffu + ((v.u >> 16) & 1u)) >> 16);
}
__device__ __forceinline__ float bf2f(u16 h) {
  union { unsigned u; float f; } v; v.u = ((unsigned)h) << 16;
  return v.f;
}

// async global->LDS, 16B per lane. LDS dest must be wave-uniform base + lane*16.
__device__ __forceinline__ void gld16(const void* g, void* l) {
  __builtin_amdgcn_global_load_lds(
      (__attribute__((address_space(1))) unsigned int*)(unsigned long long)g,
      (__attribute__((address_space(3))) unsigned int*)(unsigned)(unsigned long long)l,
      16, 0, 0);
}

__global__ void k_cast(const float* __restrict__ in, u16* __restrict__ out, int n4) {
  int i = blockIdx.x * 256 + threadIdx.x;
  if (i >= n4) return;
  float4 v = reinterpret_cast<const float4*>(in)[i];
  ushort4 o;
  o.x = f2bf(v.x); o.y = f2bf(v.y); o.z = f2bf(v.z); o.w = f2bf(v.w);
  reinterpret_cast<ushort4*>(out)[i] = o;
}

__global__ void k_trig(float2* __restrict__ trig) {
  int idx = blockIdx.x * 256 + threadIdx.x;   // T_*64 threads
  int t = idx >> 6, i = idx & 63;
  // theta_i = 10000^(-i/64) = exp(-i * ln(1e4)/64)
  float theta = __expf(-(float)i * 0.14391156831212787f);
  float f = (float)t * theta;
  float s, c;
  sincosf(f, &s, &c);
  trig[idx] = make_float2(c, s);
}

// in-place interleaved RoPE on q and k, layout [BH][T][128]
__global__ void k_rope(u16* __restrict__ qh, u16* __restrict__ kh,
                       const float2* __restrict__ trig) {
  int idx = blockIdx.x * 256 + threadIdx.x;   // 2 * 2^21 chunks of 8 elems
  u16* base = (idx >> 21) ? kh : qh;
  int c = idx & ((1 << 21) - 1);
  int t = (c >> 4) & (T_ - 1);
  int i0 = (c & 15) << 2;                      // pair index of first pair
  u16* p = base + ((size_t)c << 3);
  ushort4 a = *reinterpret_cast<ushort4*>(p);
  ushort4 bq = *reinterpret_cast<ushort4*>(p + 4);
  const float2* tr = trig + t * 64 + i0;
  float2 t0 = tr[0], t1 = tr[1], t2 = tr[2], t3 = tr[3];
  float x0, x1;
  ushort4 ra, rb;
  x0 = bf2f(a.x); x1 = bf2f(a.y);
  ra.x = f2bf(x0 * t0.x - x1 * t0.y); ra.y = f2bf(x0 * t0.y + x1 * t0.x);
  x0 = bf2f(a.z); x1 = bf2f(a.w);
  ra.z = f2bf(x0 * t1.x - x1 * t1.y); ra.w = f2bf(x0 * t1.y + x1 * t1.x);
  x0 = bf2f(bq.x); x1 = bf2f(bq.y);
  rb.x = f2bf(x0 * t2.x - x1 * t2.y); rb.y = f2bf(x0 * t2.y + x1 * t2.x);
  x0 = bf2f(bq.z); x1 = bf2f(bq.w);
  rb.z = f2bf(x0 * t3.x - x1 * t3.y); rb.w = f2bf(x0 * t3.y + x1 * t3.x);
  *reinterpret_cast<ushort4*>(p) = ra;
  *reinterpret_cast<ushort4*>(p + 4) = rb;
}

// C[M][N] = A[M][K] * Bt[N][K]^T ; 128x128 tile, 4 waves, BK=32, m97 structure.
// EPI==0: fp32 row-major out. EPI==1: qkv scatter (q,k -> [BH][T][128], v -> [BH][128][T])
template <int EPI>
__global__ __launch_bounds__(256, 2) void k_gemm(
    const u16* __restrict__ A, const u16* __restrict__ Bt,
    float* __restrict__ Cf,
    u16* __restrict__ qh, u16* __restrict__ kh, u16* __restrict__ vt,
    int Ndim, int K) {
  __shared__ alignas(16) u16 lA[128 * 32];
  __shared__ alignas(16) u16 lB[128 * 32];
  const int tid = threadIdx.x;
  const int lane = tid & 63;
  const int w = tid >> 6;
  const int wr = w >> 1, wc = w & 1;
  const int l15 = lane & 15, lq = lane >> 4;
  const long rowBase = (long)blockIdx.y * 128;
  const long colBase = (long)blockIdx.x * 128;

  const f32x4 z4 = {0.f, 0.f, 0.f, 0.f};
  f32x4 acc[4][4];
#pragma unroll
  for (int m = 0; m < 4; ++m)
#pragma unroll
    for (int n = 0; n < 4; ++n) acc[m][n] = z4;

  for (int k0 = 0; k0 < K; k0 += 32) {
#pragma unroll
    for (int i = 0; i < 2; ++i) {
      int c = tid + i * 256;               // 512 chunks of 16B per tile
      int r = c >> 2, e = (c & 3) << 3;
      gld16(A + (rowBase + r) * (long)K + k0 + e, (char*)lA + c * 16);
      gld16(Bt + (colBase + r) * (long)K + k0 + e, (char*)lB + c * 16);
    }
    __syncthreads();
    bf16x8 aF[4], bF[4];
#pragma unroll
    for (int m = 0; m < 4; ++m)
      aF[m] = *reinterpret_cast<const bf16x8*>(&lA[(wr * 64 + m * 16 + l15) * 32 + lq * 8]);
#pragma unroll
    for (int n = 0; n < 4; ++n)
      bF[n] = *reinterpret_cast<const bf16x8*>(&lB[(wc * 64 + n * 16 + l15) * 32 + lq * 8]);
#pragma unroll
    for (int m = 0; m < 4; ++m)
#pragma unroll
      for (int n = 0; n < 4; ++n)
        acc[m][n] = __builtin_amdgcn_mfma_f32_16x16x32_bf16(aF[m], bF[n], acc[m][n], 0, 0, 0);
    __syncthreads();
  }

  if (EPI == 0) {
#pragma unroll
    for (int m = 0; m < 4; ++m) {
      long row0 = rowBase + wr * 64 + m * 16 + lq * 4;
#pragma unroll
      for (int n = 0; n < 4; ++n) {
        long col = colBase + wc * 64 + n * 16 + l15;
#pragma unroll
        for (int j = 0; j < 4; ++j)
          Cf[(row0 + j) * (long)Ndim + col] = acc[m][n][j];
      }
    }
  } else {
    const int sec = (int)(colBase >> 11);          // 0=q 1=k 2=v
    const int hh = ((int)colBase >> 7) & 15;
#pragma unroll
    for (int m = 0; m < 4; ++m) {
      int row0 = (int)rowBase + wr * 64 + m * 16 + lq * 4;
      int b = row0 >> 11;
      int t0 = row0 & (T_ - 1);
      long bh = (long)b * H_ + hh;
#pragma unroll
      for (int n = 0; n < 4; ++n) {
        int dd = wc * 64 + n * 16 + l15;
        if (sec < 2) {
          u16* dst = sec ? kh : qh;
#pragma unroll
          for (int j = 0; j < 4; ++j)
            dst[(bh * T_ + t0 + j) * 128 + dd] = f2bf(acc[m][n][j]);
        } else {
          ushort4 pk;
          pk.x = f2bf(acc[m][n][0]); pk.y = f2bf(acc[m][n][1]);
          pk.z = f2bf(acc[m][n][2]); pk.w = f2bf(acc[m][n][3]);
          *reinterpret_cast<ushort4*>(&vt[(bh * 128 + dd) * T_ + t0]) = pk;
        }
      }
    }
  }
}

// flash attention: block = (qt, bh), 4 waves x 16 q-rows, KV tiles of 64, causal.
__global__ __launch_bounds__(256, 2) void k_attn(
    const u16* __restrict__ qh, const u16* __restrict__ kh,
    const u16* __restrict__ vt, u16* __restrict__ ym) {
  __shared__ alignas(16) u16 lK[64 * 128];   // [kv][d], XOR-swizzled rows
  __shared__ alignas(16) u16 lV[128 * 64];   // [d][kv], XOR-swizzled rows
  __shared__ alignas(16) u16 lP[4 * 16 * 64];
  const int tid = threadIdx.x;
  const int lane = tid & 63;
  const int w = tid >> 6;
  const int l15 = lane & 15, lq = lane >> 4;
  const int bh = blockIdx.y;
  const int qt = (int)gridDim.x - 1 - (int)blockIdx.x;  // heavy blocks first
  const int q0 = qt * 64;
  const int b = bh >> 4, hh = bh & 15;

  bf16x8 aQ[4];
  {
    const long qrow = (long)bh * T_ + q0 + w * 16 + l15;
#pragma unroll
    for (int cc = 0; cc < 4; ++cc)
      aQ[cc] = *reinterpret_cast<const bf16x8*>(&qh[qrow * 128 + cc * 32 + lq * 8]);
  }

  const f32x4 z4 = {0.f, 0.f, 0.f, 0.f};
  f32x4 oAcc[8];
#pragma unroll
  for (int n8 = 0; n8 < 8; ++n8) oAcc[n8] = z4;
  float mSt[4], lSt[4];
#pragma unroll
  for (int j = 0; j < 4; ++j) { mSt[j] = -1e30f; lSt[j] = 0.f; }

  const u16* Kbase = kh + (long)bh * T_ * 128;
  const u16* Vbase = vt + (long)bh * 128 * T_;
  u16* lPw = lP + w * (16 * 64);

  for (int jt = 0; jt <= qt; ++jt) {
    const int t0 = jt * 64;
    // stage K (64x128) and Vt (128x64): linear LDS dest, inverse-swizzled source
#pragma unroll
    for (int i = 0; i < 4; ++i) {
      int c = tid + i * 256;
      int rK = c >> 4;
      int lbK = ((c & 15) << 4) ^ ((rK & 7) << 4);
      gld16(Kbase + (long)(t0 + rK) * 128 + (lbK >> 1), (char*)lK + c * 16);
      int dV = c >> 3;
      int lbV = ((c & 7) << 4) ^ ((dV & 7) << 4);
      gld16(Vbase + (long)dV * T_ + t0 + (lbV >> 1), (char*)lV + c * 16);
    }
    __syncthreads();

    // S = Q K^T  (16 q-rows x 64 kv per wave)
    f32x4 sF[4];
#pragma unroll
    for (int n = 0; n < 4; ++n) sF[n] = z4;
#pragma unroll
    for (int n = 0; n < 4; ++n) {
      int r = n * 16 + l15;
      int rx = (r & 7) << 4;
#pragma unroll
      for (int cc = 0; cc < 4; ++cc) {
        bf16x8 bK = *reinterpret_cast<const bf16x8*>(
            (const char*)lK + r * 256 + ((cc * 64 + lq * 16) ^ rx));
        sF[n] = __builtin_amdgcn_mfma_f32_16x16x32_bf16(aQ[cc], bK, sF[n], 0, 0, 0);
      }
    }

    const bool diag = (jt == qt);
#pragma unroll
    for (int n = 0; n < 4; ++n) {
#pragma unroll
      for (int j = 0; j < 4; ++j) {
        float v = sF[n][j] * SCALE_;
        if (diag && (t0 + n * 16 + l15 > q0 + w * 16 + lq * 4 + j)) v = -1e30f;
        sF[n][j] = v;
      }
    }

    // row max (rows live in 16-lane groups -> xor butterfly 1,2,4,8)
    float tmax[4];
#pragma unroll
    for (int j = 0; j < 4; ++j)
      tmax[j] = fmaxf(fmaxf(sF[0][j], sF[1][j]), fmaxf(sF[2][j], sF[3][j]));
#pragma unroll
    for (int d = 1; d < 16; d <<= 1)
#pragma unroll
      for (int j = 0; j < 4; ++j)
        tmax[j] = fmaxf(tmax[j], __shfl_xor(tmax[j], d));

    float alpha[4], rsum[4];
#pragma unroll
    for (int j = 0; j < 4; ++j) {
      float mnew = fmaxf(mSt[j], tmax[j]);
      alpha[j] = __expf(mSt[j] - mnew);
      mSt[j] = mnew;
      rsum[j] = 0.f;
    }

    // p = exp(s-m); write P (C-layout -> swizzled LDS) for transpose to A-layout
#pragma unroll
    for (int n = 0; n < 4; ++n) {
#pragma unroll
      for (int j = 0; j < 4; ++j) {
        float p = __expf(sF[n][j] - mSt[j]);
        rsum[j] += p;
        int r = lq * 4 + j;
        int kl = n * 16 + l15;
        *(u16*)((char*)lPw + r * 128 + ((kl * 2) ^ ((r & 7) << 4))) = f2bf(p);
      }
    }
#pragma unroll
    for (int d = 1; d < 16; d <<= 1)
#pragma unroll
      for (int j = 0; j < 4; ++j)
        rsum[j] += __shfl_xor(rsum[j], d);
#pragma unroll
    for (int j = 0; j < 4; ++j) lSt[j] = lSt[j] * alpha[j] + rsum[j];

#pragma unroll
    for (int n8 = 0; n8 < 8; ++n8)
#pragma unroll
      for (int j = 0; j < 4; ++j) oAcc[n8][j] *= alpha[j];

    // read P as A-frags (same-wave LDS write->read, compiler orders)
    bf16x8 aP[2];
    {
      int rx = (l15 & 7) << 4;
#pragma unroll
      for (int cc = 0; cc < 2; ++cc)
        aP[cc] = *reinterpret_cast<const bf16x8*>(
            (const char*)lPw + l15 * 128 + ((cc * 64 + lq * 16) ^ rx));
    }
    // O += P V
#pragma unroll
    for (int n8 = 0; n8 < 8; ++n8) {
      int d = n8 * 16 + l15;
      int rx = (d & 7) << 4;
#pragma unroll
      for (int cc = 0; cc < 2; ++cc) {
        bf16x8 bV = *reinterpret_cast<const bf16x8*>(
            (const char*)lV + d * 128 + ((cc * 64 + lq * 16) ^ rx));
        oAcc[n8] = __builtin_amdgcn_mfma_f32_16x16x32_bf16(aP[cc], bV, oAcc[n8], 0, 0, 0);
      }
    }
    __syncthreads();
  }

  // epilogue: y merged [B*T][C] bf16 at col hh*128
#pragma unroll
  for (int n8 = 0; n8 < 8; ++n8) {
    int d = n8 * 16 + l15;
#pragma unroll
    for (int j = 0; j < 4; ++j) {
      int q = q0 + w * 16 + lq * 4 + j;
      ym[((long)b * T_ + q) * C_ + hh * 128 + d] = f2bf(oAcc[n8][j] / lSt[j]);
    }
  }
}

extern "C" void kernel_launch(void* const* d_in, const int* in_sizes, int n_in,
                              void* d_out, int out_size, void* d_ws, size_t ws_size,
                              hipStream_t stream) {
  (void)in_sizes; (void)n_in; (void)out_size; (void)ws_size;
  const float* x = (const float*)d_in[0];
  const float* wa = (const float*)d_in[1];
  const float* wp = (const float*)d_in[2];
  float* out = (float*)d_out;
  char* ws = (char*)d_ws;

  size_t off = 0;
  auto alloc = [&](size_t bytes) -> char* {
    char* p = ws + off;
    off += (bytes + 255) & ~(size_t)255;
    return p;
  };
  u16* xb  = (u16*)alloc((size_t)M_ * C_ * 2);    // also reused as ym after gemm1
  u16* wab = (u16*)alloc((size_t)N1_ * C_ * 2);
  u16* wpb = (u16*)alloc((size_t)C_ * C_ * 2);
  u16* qh  = (u16*)alloc((size_t)64 * T_ * 128 * 2);
  u16* kh  = (u16*)alloc((size_t)64 * T_ * 128 * 2);
  u16* vt  = (u16*)alloc((size_t)64 * 128 * T_ * 2);
  float2* trig = (float2*)alloc((size_t)T_ * 64 * 8);
  u16* ym = xb;  // alias: x_bf16 is dead after gemm1

  k_cast<<<dim3((M_ * C_ / 4) / 256), 256, 0, stream>>>(x, xb, M_ * C_ / 4);
  k_cast<<<dim3((N1_ * C_ / 4) / 256), 256, 0, stream>>>(wa, wab, N1_ * C_ / 4);
  k_cast<<<dim3((C_ * C_ / 4) / 256), 256, 0, stream>>>(wp, wpb, C_ * C_ / 4);
  k_trig<<<dim3((T_ * 64) / 256), 256, 0, stream>>>(trig);
  k_gemm<1><<<dim3(N1_ / 128, M_ / 128), 256, 0, stream>>>(
      xb, wab, nullptr, qh, kh, vt, N1_, C_);
  k_rope<<<dim3((2 * 64 * T_ * 16) / 256), 256, 0, stream>>>(qh, kh, trig);
  k_attn<<<dim3(32, 64), 256, 0, stream>>>(qh, kh, vt, ym);
  k_gemm<0><<<dim3(C_ / 128, M_ / 128), 256, 0, stream>>>(
      ym, wpb, out, nullptr, nullptr, nullptr, C_, C_);
}

// Round 2
// 493.573 us; speedup vs baseline: 1.4230x; 1.4230x over previous
//
#include <hip/hip_runtime.h>

#define B_ 4
#define T_ 2048
#define C_ 2048
#define H_ 16
#define N1_ 6144
#define M_ 8192
#define SCALE_ 0.08838834764831845f

typedef unsigned short u16;
typedef __bf16 bf16x8 __attribute__((ext_vector_type(8)));
typedef float f32x4 __attribute__((ext_vector_type(4)));
typedef float f32x16 __attribute__((ext_vector_type(16)));

__device__ __forceinline__ u16 f2bf(float f) {
  union { float f; unsigned u; } v; v.f = f;
  return (u16)((v.u + 0x7fffu + ((v.u >> 16) & 1u)) >> 16);
}
__device__ __forceinline__ float bf2f(u16 h) {
  union { unsigned u; float f; } v; v.u = ((unsigned)h) << 16;
  return v.f;
}

// async global->LDS, 16B per lane. LDS dest must be wave-uniform base + lane*16.
__device__ __forceinline__ void gld16(const void* g, void* l) {
  __builtin_amdgcn_global_load_lds(
      (__attribute__((address_space(1))) unsigned int*)(unsigned long long)g,
      (__attribute__((address_space(3))) unsigned int*)(unsigned)(unsigned long long)l,
      16, 0, 0);
}

__global__ void k_cast(const float* __restrict__ in, u16* __restrict__ out, int n4) {
  int i = blockIdx.x * 256 + threadIdx.x;
  if (i >= n4) return;
  float4 v = reinterpret_cast<const float4*>(in)[i];
  ushort4 o;
  o.x = f2bf(v.x); o.y = f2bf(v.y); o.z = f2bf(v.z); o.w = f2bf(v.w);
  reinterpret_cast<ushort4*>(out)[i] = o;
}

__global__ void k_trig(float2* __restrict__ trig) {
  int idx = blockIdx.x * 256 + threadIdx.x;   // T_*64 threads
  int t = idx >> 6, i = idx & 63;
  float theta = __expf(-(float)i * 0.14391156831212787f);
  float f = (float)t * theta;
  float s, c;
  sincosf(f, &s, &c);
  trig[idx] = make_float2(c, s);
}

// in-place interleaved RoPE on q and k, layout [BH][T][128]
__global__ void k_rope(u16* __restrict__ qh, u16* __restrict__ kh,
                       const float2* __restrict__ trig) {
  int idx = blockIdx.x * 256 + threadIdx.x;
  u16* base = (idx >> 21) ? kh : qh;
  int c = idx & ((1 << 21) - 1);
  int t = (c >> 4) & (T_ - 1);
  int i0 = (c & 15) << 2;
  u16* p = base + ((size_t)c << 3);
  ushort4 a = *reinterpret_cast<ushort4*>(p);
  ushort4 bq = *reinterpret_cast<ushort4*>(p + 4);
  const float2* tr = trig + t * 64 + i0;
  float2 t0 = tr[0], t1 = tr[1], t2 = tr[2], t3 = tr[3];
  float x0, x1;
  ushort4 ra, rb;
  x0 = bf2f(a.x); x1 = bf2f(a.y);
  ra.x = f2bf(x0 * t0.x - x1 * t0.y); ra.y = f2bf(x0 * t0.y + x1 * t0.x);
  x0 = bf2f(a.z); x1 = bf2f(a.w);
  ra.z = f2bf(x0 * t1.x - x1 * t1.y); ra.w = f2bf(x0 * t1.y + x1 * t1.x);
  x0 = bf2f(bq.x); x1 = bf2f(bq.y);
  rb.x = f2bf(x0 * t2.x - x1 * t2.y); rb.y = f2bf(x0 * t2.y + x1 * t2.x);
  x0 = bf2f(bq.z); x1 = bf2f(bq.w);
  rb.z = f2bf(x0 * t3.x - x1 * t3.y); rb.w = f2bf(x0 * t3.y + x1 * t3.x);
  *reinterpret_cast<ushort4*>(p) = ra;
  *reinterpret_cast<ushort4*>(p + 4) = rb;
}

// C[M][N] = A[M][K] * Bt[N][K]^T ; 128x128 tile, 4 waves, BK=32, m97 structure.
template <int EPI>
__global__ __launch_bounds__(256, 2) void k_gemm(
    const u16* __restrict__ A, const u16* __restrict__ Bt,
    float* __restrict__ Cf,
    u16* __restrict__ qh, u16* __restrict__ kh, u16* __restrict__ vt,
    int Ndim, int K) {
  __shared__ alignas(16) u16 lA[128 * 32];
  __shared__ alignas(16) u16 lB[128 * 32];
  const int tid = threadIdx.x;
  const int lane = tid & 63;
  const int w = tid >> 6;
  const int wr = w >> 1, wc = w & 1;
  const int l15 = lane & 15, lq = lane >> 4;
  const long rowBase = (long)blockIdx.y * 128;
  const long colBase = (long)blockIdx.x * 128;

  const f32x4 z4 = {0.f, 0.f, 0.f, 0.f};
  f32x4 acc[4][4];
#pragma unroll
  for (int m = 0; m < 4; ++m)
#pragma unroll
    for (int n = 0; n < 4; ++n) acc[m][n] = z4;

  for (int k0 = 0; k0 < K; k0 += 32) {
#pragma unroll
    for (int i = 0; i < 2; ++i) {
      int c = tid + i * 256;
      int r = c >> 2, e = (c & 3) << 3;
      gld16(A + (rowBase + r) * (long)K + k0 + e, (char*)lA + c * 16);
      gld16(Bt + (colBase + r) * (long)K + k0 + e, (char*)lB + c * 16);
    }
    __syncthreads();
    bf16x8 aF[4], bF[4];
#pragma unroll
    for (int m = 0; m < 4; ++m)
      aF[m] = *reinterpret_cast<const bf16x8*>(&lA[(wr * 64 + m * 16 + l15) * 32 + lq * 8]);
#pragma unroll
    for (int n = 0; n < 4; ++n)
      bF[n] = *reinterpret_cast<const bf16x8*>(&lB[(wc * 64 + n * 16 + l15) * 32 + lq * 8]);
#pragma unroll
    for (int m = 0; m < 4; ++m)
#pragma unroll
      for (int n = 0; n < 4; ++n)
        acc[m][n] = __builtin_amdgcn_mfma_f32_16x16x32_bf16(aF[m], bF[n], acc[m][n], 0, 0, 0);
    __syncthreads();
  }

  if (EPI == 0) {
#pragma unroll
    for (int m = 0; m < 4; ++m) {
      long row0 = rowBase + wr * 64 + m * 16 + lq * 4;
#pragma unroll
      for (int n = 0; n < 4; ++n) {
        long col = colBase + wc * 64 + n * 16 + l15;
#pragma unroll
        for (int j = 0; j < 4; ++j)
          Cf[(row0 + j) * (long)Ndim + col] = acc[m][n][j];
      }
    }
  } else {
    const int sec = (int)(colBase >> 11);          // 0=q 1=k 2=v
    const int hh = ((int)colBase >> 7) & 15;
#pragma unroll
    for (int m = 0; m < 4; ++m) {
      int row0 = (int)rowBase + wr * 64 + m * 16 + lq * 4;
      int b = row0 >> 11;
      int t0 = row0 & (T_ - 1);
      long bh = (long)b * H_ + hh;
#pragma unroll
      for (int n = 0; n < 4; ++n) {
        int dd = wc * 64 + n * 16 + l15;
        if (sec < 2) {
          u16* dst = sec ? kh : qh;
#pragma unroll
          for (int j = 0; j < 4; ++j)
            dst[(bh * T_ + t0 + j) * 128 + dd] = f2bf(acc[m][n][j]);
        } else {
          ushort4 pk;
          pk.x = f2bf(acc[m][n][0]); pk.y = f2bf(acc[m][n][1]);
          pk.z = f2bf(acc[m][n][2]); pk.w = f2bf(acc[m][n][3]);
          *reinterpret_cast<ushort4*>(&vt[(bh * 128 + dd) * T_ + t0]) = pk;
        }
      }
    }
  }
}

// pack 8 f32 P-values (S^T reg layout) into one PV A-fragment via cvt_pk + permlane32_swap
#define PACK_SLOT(dst, P, base)                                                       \
  {                                                                                   \
    unsigned ua, ub, uc, ud;                                                          \
    asm("v_cvt_pk_bf16_f32 %0, %1, %2" : "=v"(ua) : "v"(P[base + 0]), "v"(P[base + 1])); \
    asm("v_cvt_pk_bf16_f32 %0, %1, %2" : "=v"(ub) : "v"(P[base + 4]), "v"(P[base + 5])); \
    asm("v_permlane32_swap_b32 %0, %1" : "+v"(ua), "+v"(ub));                         \
    asm("v_cvt_pk_bf16_f32 %0, %1, %2" : "=v"(uc) : "v"(P[base + 2]), "v"(P[base + 3])); \
    asm("v_cvt_pk_bf16_f32 %0, %1, %2" : "=v"(ud) : "v"(P[base + 6]), "v"(P[base + 7])); \
    asm("v_permlane32_swap_b32 %0, %1" : "+v"(uc), "+v"(ud));                         \
    union { unsigned u[4]; bf16x8 v; } tt;                                            \
    tt.u[0] = ua; tt.u[1] = uc; tt.u[2] = ub; tt.u[3] = ud;                           \
    dst = tt.v;                                                                       \
  }

// flash attention, swapped-QK^T 32x32 structure.
// 4 waves x 32 q-rows = 128-row panel; block does panels (pr, 15-pr) => uniform 34 tiles.
__global__ __launch_bounds__(256, 2) void k_attn(
    const u16* __restrict__ qh, const u16* __restrict__ kh,
    const u16* __restrict__ vt, u16* __restrict__ ym) {
  __shared__ alignas(16) u16 lK[2][64 * 128];   // [kv][d] rows XOR-swizzled
  __shared__ alignas(16) u16 lV[2][128 * 64];   // [d][kv] rows XOR-swizzled
  const int tid = threadIdx.x;
  const int lane = tid & 63;
  const int w = tid >> 6;
  const int l31 = lane & 31;
  const int hi = lane >> 5;
  const int swz = (l31 & 7) << 4;
  const int id = (int)blockIdx.x;
  const int pr = id >> 6;                               // 0..7 panel pair
  const int bh = ((id & 7) << 3) | ((id >> 3) & 7);     // XCD-grouped heads
  const int b = bh >> 4, hh = bh & 15;
  const u16* Kbase = kh + (long)bh * T_ * 128;
  const u16* Vbase = vt + (long)bh * 128 * T_;
  const u16* Qbase = qh + (long)bh * T_ * 128;

  auto stage = [&](int bi, int t0) {
#pragma unroll
    for (int i = 0; i < 4; ++i) {
      int c = tid + i * 256;
      int rK = c >> 4;
      int lbK = ((c & 15) << 4) ^ ((rK & 7) << 4);
      gld16(Kbase + (long)(t0 + rK) * 128 + (lbK >> 1), (char*)(&lK[bi][0]) + c * 16);
      int dV = c >> 3;
      int lbV = ((c & 7) << 4) ^ ((dV & 7) << 4);
      gld16(Vbase + (long)dV * T_ + t0 + (lbV >> 1), (char*)(&lV[bi][0]) + c * 16);
    }
  };

#pragma unroll 1
  for (int half = 0; half < 2; ++half) {
    const int p = half ? 15 - pr : pr;
    const int NT = 2 * (p + 1);
    const int qw = p * 128 + w * 32;          // wave's first q row (within head)
    const int ntw = (qw + 95) >> 6;           // tiles this wave needs

    bf16x8 qF[8];
    {
      const u16* qrow = Qbase + (long)(qw + l31) * 128 + hi * 8;
#pragma unroll
      for (int s = 0; s < 8; ++s)
        qF[s] = *reinterpret_cast<const bf16x8*>(qrow + s * 16);
    }

    f32x16 oA[4];
#pragma unroll
    for (int n = 0; n < 4; ++n)
#pragma unroll
      for (int r = 0; r < 16; ++r) oA[n][r] = 0.f;
    float mR = -1e30f, lR = 0.f;

    stage(0, 0);
    __syncthreads();
    int cur = 0;
#pragma unroll 1
    for (int jt = 0; jt < NT; ++jt) {
      if (jt + 1 < NT) stage(cur ^ 1, (jt + 1) * 64);
      if (jt < ntw) {
        const int t0 = jt * 64;
        const char* Kc = (const char*)(&lK[cur][0]);
        const char* Vc = (const char*)(&lV[cur][0]);
        f32x16 s0, s1;
#pragma unroll
        for (int r = 0; r < 16; ++r) { s0[r] = 0.f; s1[r] = 0.f; }
        __builtin_amdgcn_s_setprio(1);
#pragma unroll
        for (int s = 0; s < 8; ++s) {
          int cb = (s * 32 + hi * 16) ^ swz;
          bf16x8 k0 = *reinterpret_cast<const bf16x8*>(Kc + l31 * 256 + cb);
          bf16x8 k1 = *reinterpret_cast<const bf16x8*>(Kc + (32 + l31) * 256 + cb);
          s0 = __builtin_amdgcn_mfma_f32_32x32x16_bf16(k0, qF[s], s0, 0, 0, 0);
          s1 = __builtin_amdgcn_mfma_f32_32x32x16_bf16(k1, qF[s], s1, 0, 0, 0);
        }
        __builtin_amdgcn_s_setprio(0);

        // softmax (S^T layout: lane owns q = qw+l31; kv = t0 + crow(r,hi) [+32 for s1])
        float f0[16], f1[16];
#pragma unroll
        for (int r = 0; r < 16; ++r) { f0[r] = s0[r] * SCALE_; f1[r] = s1[r] * SCALE_; }
        if (jt == ntw - 1) {
          const int qa = qw + l31;
#pragma unroll
          for (int r = 0; r < 16; ++r) {
            int kv = t0 + (r & 3) + 8 * (r >> 2) + 4 * hi;
            if (kv > qa) f0[r] = -1e30f;
            if (kv + 32 > qa) f1[r] = -1e30f;
          }
        }
        float mt = fmaxf(f0[0], f1[0]);
#pragma unroll
        for (int r = 1; r < 16; ++r) mt = fmaxf(mt, fmaxf(f0[r], f1[r]));
        mt = fmaxf(mt, __shfl_xor(mt, 32));
        float mN = fmaxf(mR, mt);
        float al = __expf(mR - mN);
        mR = mN;
        float rs = 0.f;
#pragma unroll
        for (int r = 0; r < 16; ++r) {
          f0[r] = __expf(f0[r] - mN);
          f1[r] = __expf(f1[r] - mN);
          rs += f0[r] + f1[r];
        }
        rs += __shfl_xor(rs, 32);
        lR = lR * al + rs;
        float aR[16];
#pragma unroll
        for (int r = 0; r < 16; ++r)
          aR[r] = __shfl(al, (r & 3) + 8 * (r >> 2) + 4 * hi);
#pragma unroll
        for (int n = 0; n < 4; ++n)
#pragma unroll
          for (int r = 0; r < 16; ++r) oA[n][r] *= aR[r];

        bf16x8 paF[4];
        PACK_SLOT(paF[0], f0, 0);
        PACK_SLOT(paF[1], f0, 8);
        PACK_SLOT(paF[2], f1, 0);
        PACK_SLOT(paF[3], f1, 8);

        __builtin_amdgcn_s_setprio(1);
#pragma unroll
        for (int n = 0; n < 4; ++n) {
          const char* vrow = Vc + (n * 32 + l31) * 128;
#pragma unroll
          for (int ks = 0; ks < 4; ++ks) {
            bf16x8 bV = *reinterpret_cast<const bf16x8*>(vrow + ((ks * 32 + hi * 16) ^ swz));
            oA[n] = __builtin_amdgcn_mfma_f32_32x32x16_bf16(paF[ks], bV, oA[n], 0, 0, 0);
          }
        }
        __builtin_amdgcn_s_setprio(0);
      }
      __syncthreads();
      cur ^= 1;
    }

    // epilogue: O[q][d] / l  ->  ym row-major [B*T][C]
    float li = 1.f / lR;
    float liR[16];
#pragma unroll
    for (int r = 0; r < 16; ++r)
      liR[r] = __shfl(li, (r & 3) + 8 * (r >> 2) + 4 * hi);
    u16* yrow = ym + ((long)b * T_ + qw) * C_ + hh * 128 + l31;
#pragma unroll
    for (int n = 0; n < 4; ++n)
#pragma unroll
      for (int r = 0; r < 16; ++r) {
        int cr = (r & 3) + 8 * (r >> 2) + 4 * hi;
        yrow[(long)cr * C_ + n * 32] = f2bf(oA[n][r] * liR[r]);
      }
  }
}

extern "C" void kernel_launch(void* const* d_in, const int* in_sizes, int n_in,
                              void* d_out, int out_size, void* d_ws, size_t ws_size,
                              hipStream_t stream) {
  (void)in_sizes; (void)n_in; (void)out_size; (void)ws_size;
  const float* x = (const float*)d_in[0];
  const float* wa = (const float*)d_in[1];
  const float* wp = (const float*)d_in[2];
  float* out = (float*)d_out;
  char* ws = (char*)d_ws;

  size_t off = 0;
  auto alloc = [&](size_t bytes) -> char* {
    char* p = ws + off;
    off += (bytes + 255) & ~(size_t)255;
    return p;
  };
  u16* xb  = (u16*)alloc((size_t)M_ * C_ * 2);    // reused as ym after gemm1
  u16* wab = (u16*)alloc((size_t)N1_ * C_ * 2);
  u16* wpb = (u16*)alloc((size_t)C_ * C_ * 2);
  u16* qh  = (u16*)alloc((size_t)64 * T_ * 128 * 2);
  u16* kh  = (u16*)alloc((size_t)64 * T_ * 128 * 2);
  u16* vt  = (u16*)alloc((size_t)64 * 128 * T_ * 2);
  float2* trig = (float2*)alloc((size_t)T_ * 64 * 8);
  u16* ym = xb;

  k_cast<<<dim3((M_ * C_ / 4) / 256), 256, 0, stream>>>(x, xb, M_ * C_ / 4);
  k_cast<<<dim3((N1_ * C_ / 4) / 256), 256, 0, stream>>>(wa, wab, N1_ * C_ / 4);
  k_cast<<<dim3((C_ * C_ / 4) / 256), 256, 0, stream>>>(wp, wpb, C_ * C_ / 4);
  k_trig<<<dim3((T_ * 64) / 256), 256, 0, stream>>>(trig);
  k_gemm<1><<<dim3(N1_ / 128, M_ / 128), 256, 0, stream>>>(
      xb, wab, nullptr, qh, kh, vt, N1_, C_);
  k_rope<<<dim3((2 * 64 * T_ * 16) / 256), 256, 0, stream>>>(qh, kh, trig);
  k_attn<<<dim3(512), 256, 0, stream>>>(qh, kh, vt, ym);
  k_gemm<0><<<dim3(C_ / 128, M_ / 128), 256, 0, stream>>>(
      ym, wpb, out, nullptr, nullptr, nullptr, C_, C_);
}

// Round 3
// 463.347 us; speedup vs baseline: 1.5159x; 1.0652x over previous
//
#include <hip/hip_runtime.h>

#define B_ 4
#define T_ 2048
#define C_ 2048
#define H_ 16
#define N1_ 6144
#define M_ 8192
#define SCALE_ 0.08838834764831845f

typedef unsigned short u16;
typedef __bf16 bf16x8 __attribute__((ext_vector_type(8)));
typedef float f32x4 __attribute__((ext_vector_type(4)));
typedef float f32x16 __attribute__((ext_vector_type(16)));

__device__ __forceinline__ u16 f2bf(float f) {
  union { float f; unsigned u; } v; v.f = f;
  return (u16)((v.u + 0x7fffu + ((v.u >> 16) & 1u)) >> 16);
}
__device__ __forceinline__ float bf2f(u16 h) {
  union { unsigned u; float f; } v; v.u = ((unsigned)h) << 16;
  return v.f;
}

// async global->LDS, 16B per lane. LDS dest must be wave-uniform base + lane*16.
__device__ __forceinline__ void gld16(const void* g, void* l) {
  __builtin_amdgcn_global_load_lds(
      (__attribute__((address_space(1))) unsigned int*)(unsigned long long)g,
      (__attribute__((address_space(3))) unsigned int*)(unsigned)(unsigned long long)l,
      16, 0, 0);
}

__global__ void k_cast(const float* __restrict__ in, u16* __restrict__ out, int n4) {
  int i = blockIdx.x * 256 + threadIdx.x;
  if (i >= n4) return;
  float4 v = reinterpret_cast<const float4*>(in)[i];
  ushort4 o;
  o.x = f2bf(v.x); o.y = f2bf(v.y); o.z = f2bf(v.z); o.w = f2bf(v.w);
  reinterpret_cast<ushort4*>(out)[i] = o;
}

__global__ void k_trig(float2* __restrict__ trig) {
  int idx = blockIdx.x * 256 + threadIdx.x;   // T_*64 threads
  int t = idx >> 6, i = idx & 63;
  float theta = __expf(-(float)i * 0.14391156831212787f);
  float f = (float)t * theta;
  float s, c;
  sincosf(f, &s, &c);
  trig[idx] = make_float2(c, s);
}

// C[M][N] = A[M][K=2048] * Bt[N][K]^T ; BM=256 BN=128 BK=64; 8 waves (4m x 2n);
// 3-slot LDS ring, 2 phases/K-tile, counted vmcnt(6), T2 swizzle, T5 setprio.
// EPI==0: fp32 row-major out (N=2048). EPI==1: qkv scatter with fused RoPE on q,k.
template <int EPI>
__global__ __launch_bounds__(512, 2) void k_gemm8(
    const u16* __restrict__ A, const u16* __restrict__ Bt,
    float* __restrict__ Cf,
    u16* __restrict__ qh, u16* __restrict__ kh, u16* __restrict__ vt,
    const float2* __restrict__ trig, int nbx, int cpx) {
  __shared__ alignas(16) u16 lA[3 * 256 * 64];
  __shared__ alignas(16) u16 lB[3 * 128 * 64];
  const int tid = threadIdx.x;
  const int lane = tid & 63;
  const int w = tid >> 6;                 // 0..7
  const int wr = w >> 1, wc = w & 1;      // 4m x 2n
  const int l15 = lane & 15, lq = lane >> 4;
  const int rs = l15 & 7;                 // read-side swizzle

  const int id = (int)blockIdx.x;
  const int swz = (id & 7) * cpx + (id >> 3);   // bijective XCD swizzle (nwg%8==0)
  const int bx = swz % nbx, by = swz / nbx;
  const long rowBase = (long)by * 256;
  const long colBase = (long)bx * 128;
  const u16* Ag = A + rowBase * 2048;
  const u16* Bg = Bt + colBase * 2048;

  const f32x4 z4 = {0.f, 0.f, 0.f, 0.f};
  f32x4 acc[4][4];
#pragma unroll
  for (int m = 0; m < 4; ++m)
#pragma unroll
    for (int n = 0; n < 4; ++n) acc[m][n] = z4;

  // ---- prologue: stage tiles 0,1 into slots 0,1 (6 loads/thread each)
#pragma unroll
  for (int pt = 0; pt < 2; ++pt) {
    char* Ad = (char*)lA + pt * 32768;
    char* Bd = (char*)lB + pt * 16384;
    const long kG = (long)pt * 64;
#pragma unroll
    for (int q = 0; q < 4; ++q) {
      int c = tid + q * 512;
      gld16(Ag + (long)(c >> 3) * 2048 + kG + (((c & 7) ^ ((c >> 3) & 7)) << 3),
            Ad + c * 16);
    }
#pragma unroll
    for (int q = 0; q < 2; ++q) {
      int c = tid + q * 512;
      gld16(Bg + (long)(c >> 3) * 2048 + kG + (((c & 7) ^ ((c >> 3) & 7)) << 3),
            Bd + c * 16);
    }
  }
  asm volatile("s_waitcnt vmcnt(6)" ::: "memory");  // tile0 landed; tile1 in flight
  __builtin_amdgcn_s_barrier();

  int slot = 0;
#pragma unroll 1
  for (int t = 0; t < 32; ++t) {
    const char* As = (const char*)lA + slot * 32768;
    const char* Bs = (const char*)lB + slot * 16384;
    int s2 = slot + 2; if (s2 >= 3) s2 -= 3;
    char* Ad = (char*)lA + s2 * 32768;
    char* Bd = (char*)lB + s2 * 16384;
    const long kG = (long)(t + 2) * 64;
    const bool st = (t < 30);

    bf16x8 aF[4], bF[4];
    // ---------- phase 0 : k-half 0 ----------
#pragma unroll
    for (int fm = 0; fm < 4; ++fm)
      aF[fm] = *reinterpret_cast<const bf16x8*>(
          As + (wr * 64 + fm * 16 + l15) * 128 + ((lq ^ rs) << 4));
#pragma unroll
    for (int fn = 0; fn < 4; ++fn)
      bF[fn] = *reinterpret_cast<const bf16x8*>(
          Bs + (wc * 64 + fn * 16 + l15) * 128 + ((lq ^ rs) << 4));
    if (st) {
#pragma unroll
      for (int q = 0; q < 3; ++q) {
        int c = tid + q * 512;
        gld16(Ag + (long)(c >> 3) * 2048 + kG + (((c & 7) ^ ((c >> 3) & 7)) << 3),
              Ad + c * 16);
      }
    }
    __builtin_amdgcn_s_barrier();
    __builtin_amdgcn_s_setprio(1);
#pragma unroll
    for (int fm = 0; fm < 4; ++fm)
#pragma unroll
      for (int fn = 0; fn < 4; ++fn)
        acc[fm][fn] =
            __builtin_amdgcn_mfma_f32_16x16x32_bf16(aF[fm], bF[fn], acc[fm][fn], 0, 0, 0);
    __builtin_amdgcn_s_setprio(0);
    __builtin_amdgcn_s_barrier();
    // ---------- phase 1 : k-half 1 ----------
#pragma unroll
    for (int fm = 0; fm < 4; ++fm)
      aF[fm] = *reinterpret_cast<const bf16x8*>(
          As + (wr * 64 + fm * 16 + l15) * 128 + (((4 | lq) ^ rs) << 4));
#pragma unroll
    for (int fn = 0; fn < 4; ++fn)
      bF[fn] = *reinterpret_cast<const bf16x8*>(
          Bs + (wc * 64 + fn * 16 + l15) * 128 + (((4 | lq) ^ rs) << 4));
    if (st) {
      {
        int c = tid + 1536;
        gld16(Ag + (long)(c >> 3) * 2048 + kG + (((c & 7) ^ ((c >> 3) & 7)) << 3),
              Ad + c * 16);
      }
#pragma unroll
      for (int q = 0; q < 2; ++q) {
        int c = tid + q * 512;
        gld16(Bg + (long)(c >> 3) * 2048 + kG + (((c & 7) ^ ((c >> 3) & 7)) << 3),
              Bd + c * 16);
      }
    }
    __builtin_amdgcn_s_barrier();
    __builtin_amdgcn_s_setprio(1);
#pragma unroll
    for (int fm = 0; fm < 4; ++fm)
#pragma unroll
      for (int fn = 0; fn < 4; ++fn)
        acc[fm][fn] =
            __builtin_amdgcn_mfma_f32_16x16x32_bf16(aF[fm], bF[fn], acc[fm][fn], 0, 0, 0);
    __builtin_amdgcn_s_setprio(0);
    if (st) asm volatile("s_waitcnt vmcnt(6)" ::: "memory");   // tile t+1 landed
    else    asm volatile("s_waitcnt vmcnt(0)" ::: "memory");   // drain tail
    __builtin_amdgcn_s_barrier();
    slot = (slot == 2) ? 0 : slot + 1;
  }

  if (EPI == 0) {
#pragma unroll
    for (int m = 0; m < 4; ++m) {
      long row0 = rowBase + wr * 64 + m * 16 + lq * 4;
#pragma unroll
      for (int n = 0; n < 4; ++n) {
        long col = colBase + wc * 64 + n * 16 + l15;
#pragma unroll
        for (int j = 0; j < 4; ++j)
          Cf[(row0 + j) * 2048 + col] = acc[m][n][j];
      }
    }
  } else {
    const int sec = (int)(colBase >> 11);          // 0=q 1=k 2=v
    const int hh = ((int)colBase >> 7) & 15;
#pragma unroll
    for (int m = 0; m < 4; ++m) {
      int row0 = (int)rowBase + wr * 64 + m * 16 + lq * 4;
      int b = row0 >> 11;
      int t0 = row0 & (T_ - 1);
      long bh = (long)b * H_ + hh;
#pragma unroll
      for (int n = 0; n < 4; ++n) {
        int dd = wc * 64 + n * 16 + l15;
        if (sec < 2) {
          u16* dst = sec ? kh : qh;
#pragma unroll
          for (int j = 0; j < 4; ++j) {
            float v = acc[m][n][j];
            float vp = __shfl_xor(v, 1);
            float2 cs = trig[(t0 + j) * 64 + (dd >> 1)];
            float r = (dd & 1) ? (vp * cs.y + v * cs.x) : (v * cs.x - vp * cs.y);
            dst[(bh * T_ + t0 + j) * 128 + dd] = f2bf(r);
          }
        } else {
          ushort4 pk;
          pk.x = f2bf(acc[m][n][0]); pk.y = f2bf(acc[m][n][1]);
          pk.z = f2bf(acc[m][n][2]); pk.w = f2bf(acc[m][n][3]);
          *reinterpret_cast<ushort4*>(&vt[(bh * 128 + dd) * T_ + t0]) = pk;
        }
      }
    }
  }
}

// pack 8 f32 P-values (S^T reg layout) into one PV A-fragment via cvt_pk + permlane32_swap
#define PACK_SLOT(dst, P, base)                                                       \
  {                                                                                   \
    unsigned ua, ub, uc, ud;                                                          \
    asm("v_cvt_pk_bf16_f32 %0, %1, %2" : "=v"(ua) : "v"(P[base + 0]), "v"(P[base + 1])); \
    asm("v_cvt_pk_bf16_f32 %0, %1, %2" : "=v"(ub) : "v"(P[base + 4]), "v"(P[base + 5])); \
    asm("v_permlane32_swap_b32 %0, %1" : "+v"(ua), "+v"(ub));                         \
    asm("v_cvt_pk_bf16_f32 %0, %1, %2" : "=v"(uc) : "v"(P[base + 2]), "v"(P[base + 3])); \
    asm("v_cvt_pk_bf16_f32 %0, %1, %2" : "=v"(ud) : "v"(P[base + 6]), "v"(P[base + 7])); \
    asm("v_permlane32_swap_b32 %0, %1" : "+v"(uc), "+v"(ud));                         \
    union { unsigned u[4]; bf16x8 v; } tt;                                            \
    tt.u[0] = ua; tt.u[1] = uc; tt.u[2] = ub; tt.u[3] = ud;                           \
    dst = tt.v;                                                                       \
  }

// flash attention, swapped-QK^T 32x32 structure.
__global__ __launch_bounds__(256, 2) void k_attn(
    const u16* __restrict__ qh, const u16* __restrict__ kh,
    const u16* __restrict__ vt, u16* __restrict__ ym) {
  __shared__ alignas(16) u16 lK[2][64 * 128];
  __shared__ alignas(16) u16 lV[2][128 * 64];
  const int tid = threadIdx.x;
  const int lane = tid & 63;
  const int w = tid >> 6;
  const int l31 = lane & 31;
  const int hi = lane >> 5;
  const int swz = (l31 & 7) << 4;
  const int id = (int)blockIdx.x;
  const int pr = id >> 6;
  const int bh = ((id & 7) << 3) | ((id >> 3) & 7);
  const int b = bh >> 4, hh = bh & 15;
  const u16* Kbase = kh + (long)bh * T_ * 128;
  const u16* Vbase = vt + (long)bh * 128 * T_;
  const u16* Qbase = qh + (long)bh * T_ * 128;

  auto stage = [&](int bi, int t0) {
#pragma unroll
    for (int i = 0; i < 4; ++i) {
      int c = tid + i * 256;
      int rK = c >> 4;
      int lbK = ((c & 15) << 4) ^ ((rK & 7) << 4);
      gld16(Kbase + (long)(t0 + rK) * 128 + (lbK >> 1), (char*)(&lK[bi][0]) + c * 16);
      int dV = c >> 3;
      int lbV = ((c & 7) << 4) ^ ((dV & 7) << 4);
      gld16(Vbase + (long)dV * T_ + t0 + (lbV >> 1), (char*)(&lV[bi][0]) + c * 16);
    }
  };

#pragma unroll 1
  for (int half = 0; half < 2; ++half) {
    const int p = half ? 15 - pr : pr;
    const int NT = 2 * (p + 1);
    const int qw = p * 128 + w * 32;
    const int ntw = (qw + 95) >> 6;

    bf16x8 qF[8];
    {
      const u16* qrow = Qbase + (long)(qw + l31) * 128 + hi * 8;
#pragma unroll
      for (int s = 0; s < 8; ++s)
        qF[s] = *reinterpret_cast<const bf16x8*>(qrow + s * 16);
    }

    f32x16 oA[4];
#pragma unroll
    for (int n = 0; n < 4; ++n)
#pragma unroll
      for (int r = 0; r < 16; ++r) oA[n][r] = 0.f;
    float mR = -1e30f, lR = 0.f;

    stage(0, 0);
    __syncthreads();
    int cur = 0;
#pragma unroll 1
    for (int jt = 0; jt < NT; ++jt) {
      if (jt + 1 < NT) stage(cur ^ 1, (jt + 1) * 64);
      if (jt < ntw) {
        const int t0 = jt * 64;
        const char* Kc = (const char*)(&lK[cur][0]);
        const char* Vc = (const char*)(&lV[cur][0]);
        f32x16 s0, s1;
#pragma unroll
        for (int r = 0; r < 16; ++r) { s0[r] = 0.f; s1[r] = 0.f; }
        __builtin_amdgcn_s_setprio(1);
#pragma unroll
        for (int s = 0; s < 8; ++s) {
          int cb = (s * 32 + hi * 16) ^ swz;
          bf16x8 k0 = *reinterpret_cast<const bf16x8*>(Kc + l31 * 256 + cb);
          bf16x8 k1 = *reinterpret_cast<const bf16x8*>(Kc + (32 + l31) * 256 + cb);
          s0 = __builtin_amdgcn_mfma_f32_32x32x16_bf16(k0, qF[s], s0, 0, 0, 0);
          s1 = __builtin_amdgcn_mfma_f32_32x32x16_bf16(k1, qF[s], s1, 0, 0, 0);
        }
        __builtin_amdgcn_s_setprio(0);

        float f0[16], f1[16];
#pragma unroll
        for (int r = 0; r < 16; ++r) { f0[r] = s0[r] * SCALE_; f1[r] = s1[r] * SCALE_; }
        if (jt == ntw - 1) {
          const int qa = qw + l31;
#pragma unroll
          for (int r = 0; r < 16; ++r) {
            int kv = t0 + (r & 3) + 8 * (r >> 2) + 4 * hi;
            if (kv > qa) f0[r] = -1e30f;
            if (kv + 32 > qa) f1[r] = -1e30f;
          }
        }
        float mt = fmaxf(f0[0], f1[0]);
#pragma unroll
        for (int r = 1; r < 16; ++r) mt = fmaxf(mt, fmaxf(f0[r], f1[r]));
        mt = fmaxf(mt, __shfl_xor(mt, 32));
        float mN = fmaxf(mR, mt);
        float al = __expf(mR - mN);
        mR = mN;
        float rs = 0.f;
#pragma unroll
        for (int r = 0; r < 16; ++r) {
          f0[r] = __expf(f0[r] - mN);
          f1[r] = __expf(f1[r] - mN);
          rs += f0[r] + f1[r];
        }
        rs += __shfl_xor(rs, 32);
        lR = lR * al + rs;
        float aR[16];
#pragma unroll
        for (int r = 0; r < 16; ++r)
          aR[r] = __shfl(al, (r & 3) + 8 * (r >> 2) + 4 * hi);
#pragma unroll
        for (int n = 0; n < 4; ++n)
#pragma unroll
          for (int r = 0; r < 16; ++r) oA[n][r] *= aR[r];

        bf16x8 paF[4];
        PACK_SLOT(paF[0], f0, 0);
        PACK_SLOT(paF[1], f0, 8);
        PACK_SLOT(paF[2], f1, 0);
        PACK_SLOT(paF[3], f1, 8);

        __builtin_amdgcn_s_setprio(1);
#pragma unroll
        for (int n = 0; n < 4; ++n) {
          const char* vrow = Vc + (n * 32 + l31) * 128;
#pragma unroll
          for (int ks = 0; ks < 4; ++ks) {
            bf16x8 bV = *reinterpret_cast<const bf16x8*>(vrow + ((ks * 32 + hi * 16) ^ swz));
            oA[n] = __builtin_amdgcn_mfma_f32_32x32x16_bf16(paF[ks], bV, oA[n], 0, 0, 0);
          }
        }
        __builtin_amdgcn_s_setprio(0);
      }
      __syncthreads();
      cur ^= 1;
    }

    float li = 1.f / lR;
    float liR[16];
#pragma unroll
    for (int r = 0; r < 16; ++r)
      liR[r] = __shfl(li, (r & 3) + 8 * (r >> 2) + 4 * hi);
    u16* yrow = ym + ((long)b * T_ + qw) * C_ + hh * 128 + l31;
#pragma unroll
    for (int n = 0; n < 4; ++n)
#pragma unroll
      for (int r = 0; r < 16; ++r) {
        int cr = (r & 3) + 8 * (r >> 2) + 4 * hi;
        yrow[(long)cr * C_ + n * 32] = f2bf(oA[n][r] * liR[r]);
      }
  }
}

extern "C" void kernel_launch(void* const* d_in, const int* in_sizes, int n_in,
                              void* d_out, int out_size, void* d_ws, size_t ws_size,
                              hipStream_t stream) {
  (void)in_sizes; (void)n_in; (void)out_size; (void)ws_size;
  const float* x = (const float*)d_in[0];
  const float* wa = (const float*)d_in[1];
  const float* wp = (const float*)d_in[2];
  float* out = (float*)d_out;
  char* ws = (char*)d_ws;

  size_t off = 0;
  auto alloc = [&](size_t bytes) -> char* {
    char* p = ws + off;
    off += (bytes + 255) & ~(size_t)255;
    return p;
  };
  u16* xb  = (u16*)alloc((size_t)M_ * C_ * 2);    // reused as ym after gemm1
  u16* wab = (u16*)alloc((size_t)N1_ * C_ * 2);
  u16* wpb = (u16*)alloc((size_t)C_ * C_ * 2);
  u16* qh  = (u16*)alloc((size_t)64 * T_ * 128 * 2);
  u16* kh  = (u16*)alloc((size_t)64 * T_ * 128 * 2);
  u16* vt  = (u16*)alloc((size_t)64 * 128 * T_ * 2);
  float2* trig = (float2*)alloc((size_t)T_ * 64 * 8);
  u16* ym = xb;

  k_cast<<<dim3((M_ * C_ / 4) / 256), 256, 0, stream>>>(x, xb, M_ * C_ / 4);
  k_cast<<<dim3((N1_ * C_ / 4) / 256), 256, 0, stream>>>(wa, wab, N1_ * C_ / 4);
  k_cast<<<dim3((C_ * C_ / 4) / 256), 256, 0, stream>>>(wp, wpb, C_ * C_ / 4);
  k_trig<<<dim3((T_ * 64) / 256), 256, 0, stream>>>(trig);
  // GEMM1: M=8192, N=6144 -> grid 48*32=1536 blocks (nbx=48, cpx=192)
  k_gemm8<1><<<dim3(1536), 512, 0, stream>>>(
      xb, wab, nullptr, qh, kh, vt, trig, 48, 192);
  k_attn<<<dim3(512), 256, 0, stream>>>(qh, kh, vt, ym);
  // GEMM2: M=8192, N=2048 -> grid 16*32=512 blocks (nbx=16, cpx=64)
  k_gemm8<0><<<dim3(512), 512, 0, stream>>>(
      ym, wpb, out, nullptr, nullptr, nullptr, nullptr, 16, 64);
}

// Round 4
// 414.162 us; speedup vs baseline: 1.6959x; 1.1188x over previous
//
#include <hip/hip_runtime.h>

#define B_ 4
#define T_ 2048
#define C_ 2048
#define H_ 16
#define N1_ 6144
#define M_ 8192
#define SCALE_ 0.08838834764831845f

typedef unsigned short u16;
typedef __bf16 bf16x8 __attribute__((ext_vector_type(8)));
typedef float f32x4 __attribute__((ext_vector_type(4)));
typedef float f32x16 __attribute__((ext_vector_type(16)));

__device__ __forceinline__ u16 f2bf(float f) {
  union { float f; unsigned u; } v; v.f = f;
  return (u16)((v.u + 0x7fffu + ((v.u >> 16) & 1u)) >> 16);
}
__device__ __forceinline__ float bf2f(u16 h) {
  union { unsigned u; float f; } v; v.u = ((unsigned)h) << 16;
  return v.f;
}

// async global->LDS, 16B per lane. LDS dest must be wave-uniform base + lane*16.
__device__ __forceinline__ void gld16(const void* g, void* l) {
  __builtin_amdgcn_global_load_lds(
      (__attribute__((address_space(1))) unsigned int*)(unsigned long long)g,
      (__attribute__((address_space(3))) unsigned int*)(unsigned)(unsigned long long)l,
      16, 0, 0);
}

__global__ void k_cast(const float* __restrict__ in, u16* __restrict__ out, int n4) {
  int i = blockIdx.x * 256 + threadIdx.x;
  if (i >= n4) return;
  float4 v = reinterpret_cast<const float4*>(in)[i];
  ushort4 o;
  o.x = f2bf(v.x); o.y = f2bf(v.y); o.z = f2bf(v.z); o.w = f2bf(v.w);
  reinterpret_cast<ushort4*>(out)[i] = o;
}

__global__ void k_trig(float2* __restrict__ trig) {
  int idx = blockIdx.x * 256 + threadIdx.x;   // T_*64 threads
  int t = idx >> 6, i = idx & 63;
  float theta = __expf(-(float)i * 0.14391156831212787f);
  float f = (float)t * theta;
  float s, c;
  sincosf(f, &s, &c);
  trig[idx] = make_float2(c, s);
}

// ---- 256x256 8-phase GEMM (m201 template, plain HIP) -----------------------
// C[M][N] = A[M][2048] * Bt[N][2048]^T ; BM=BN=256 BK=64; 8 waves (2M x 4N);
// per-wave 128x64; 2 LDS buffers; 8 phases / 2 K-tiles; counted vmcnt(4) at
// phases 4,8; T2 XOR swizzle; T5 setprio. EPI==0: fp32 out; EPI==1: qkv+RoPE.
// Staging halves: A-half h = rows with bit6==h (64-row stripes), B-half h =
// rows with bit5==h (32-row stripes) => each half's last quadrant-read
// precedes its restage phase.

#define STAGE_H(BUF, AB, HALF, KT, GSH)                                          \
  {                                                                              \
    _Pragma("unroll") for (int q = 0; q < 2; ++q) {                              \
      int c = tid + q * 512;                                                     \
      int idx = c >> 3;                                                          \
      int row = (idx & ((1 << (GSH)) - 1)) + ((HALF) << (GSH)) +                 \
                ((idx >> (GSH)) << ((GSH) + 1));                                 \
      gld16(((AB) ? Bg : Ag) + (long)row * 2048 + (long)(KT) * 64 +              \
                (((c & 7) ^ (idx & 7)) << 3),                                    \
            (char*)&lds[BUF][AB][row * 64 + (c & 7) * 8]);                       \
    }                                                                            \
  }

#define PHASE(BUF, MH, NH, RDA, RDB, STAGE_CODE, WAIT_CODE)                      \
  {                                                                              \
    if (RDA) {                                                                   \
      _Pragma("unroll") for (int fr = 0; fr < 4; ++fr)                           \
        _Pragma("unroll") for (int ks = 0; ks < 2; ++ks)                         \
          aCur[fr][ks] = *reinterpret_cast<const bf16x8*>(                       \
              &lds[BUF][0][(wm * 128 + (MH) * 64 + fr * 16 + l15) * 64 +         \
                           (((ks * 4 + lq) ^ swl) << 3)]);                       \
    }                                                                            \
    if (RDB) {                                                                   \
      _Pragma("unroll") for (int fc = 0; fc < 2; ++fc)                           \
        _Pragma("unroll") for (int ks = 0; ks < 2; ++ks)                         \
          bKp[NH][fc][ks] = *reinterpret_cast<const bf16x8*>(                    \
              &lds[BUF][1][(wn * 64 + (NH) * 32 + fc * 16 + l15) * 64 +          \
                           (((ks * 4 + lq) ^ swl) << 3)]);                       \
    }                                                                            \
    STAGE_CODE;                                                                  \
    __builtin_amdgcn_s_barrier();                                                \
    __builtin_amdgcn_s_setprio(1);                                               \
    _Pragma("unroll") for (int fr = 0; fr < 4; ++fr)                             \
      _Pragma("unroll") for (int fc = 0; fc < 2; ++fc)                           \
        _Pragma("unroll") for (int ks = 0; ks < 2; ++ks)                         \
          acc[(MH) * 4 + fr][(NH) * 2 + fc] =                                    \
              __builtin_amdgcn_mfma_f32_16x16x32_bf16(                           \
                  aCur[fr][ks], bKp[NH][fc][ks],                                 \
                  acc[(MH) * 4 + fr][(NH) * 2 + fc], 0, 0, 0);                   \
    __builtin_amdgcn_s_setprio(0);                                               \
    WAIT_CODE;                                                                   \
    __builtin_amdgcn_s_barrier();                                                \
  }

template <int EPI>
__global__ __launch_bounds__(512, 2) void k_gemm8(
    const u16* __restrict__ A, const u16* __restrict__ Bt,
    float* __restrict__ Cf,
    u16* __restrict__ qh, u16* __restrict__ kh, u16* __restrict__ vt,
    const float2* __restrict__ trig, int nbx, int cpx) {
  __shared__ alignas(16) u16 lds[2][2][256 * 64];
  const int tid = threadIdx.x;
  const int lane = tid & 63;
  const int w = tid >> 6;
  const int wm = w >> 2;          // 2 M-waves
  const int wn = w & 3;           // 4 N-waves
  const int l15 = lane & 15, lq = lane >> 4;
  const int swl = l15 & 7;

  const int id = (int)blockIdx.x;
  const int swz = (id & 7) * cpx + (id >> 3);   // bijective (grid % 8 == 0)
  const int bx = swz % nbx, by = swz / nbx;
  const long rowBase = (long)by * 256;
  const long colBase = (long)bx * 256;
  const u16* Ag = A + rowBase * 2048;
  const u16* Bg = Bt + colBase * 2048;

  const f32x4 z4 = {0.f, 0.f, 0.f, 0.f};
  f32x4 acc[8][4];
#pragma unroll
  for (int m = 0; m < 8; ++m)
#pragma unroll
    for (int n = 0; n < 4; ++n) acc[m][n] = z4;
  bf16x8 aCur[4][2], bKp[2][2][2];

  // prologue: tile0 -> buf0 (all 4 halves), tile1 -> buf1 halves A0,B0
  STAGE_H(0, 0, 0, 0, 6); STAGE_H(0, 1, 0, 0, 5);
  STAGE_H(0, 0, 1, 0, 6); STAGE_H(0, 1, 1, 0, 5);
  STAGE_H(1, 0, 0, 1, 6); STAGE_H(1, 1, 0, 1, 5);
  asm volatile("s_waitcnt vmcnt(4)" ::: "memory");
  __builtin_amdgcn_s_barrier();

#pragma unroll 1
  for (int i = 0; i < 16; ++i) {
    const int t1 = 2 * i + 1, t2 = 2 * i + 2, t3 = 2 * i + 3;
    const bool st = (i < 15);
    PHASE(0, 0, 0, 1, 1, STAGE_H(1, 0, 1, t1, 6), );
    PHASE(0, 0, 1, 0, 1, STAGE_H(1, 1, 1, t1, 5), );
    PHASE(0, 1, 0, 1, 0, if (st) STAGE_H(0, 0, 0, t2, 6), );
    PHASE(0, 1, 1, 0, 0, if (st) STAGE_H(0, 1, 0, t2, 5),
          if (st) { asm volatile("s_waitcnt vmcnt(4)" ::: "memory"); }
          else    { asm volatile("s_waitcnt vmcnt(0)" ::: "memory"); });
    PHASE(1, 0, 0, 1, 1, if (st) STAGE_H(0, 0, 1, t2, 6), );
    PHASE(1, 0, 1, 0, 1, if (st) STAGE_H(0, 1, 1, t2, 5), );
    PHASE(1, 1, 0, 1, 0, if (st) STAGE_H(1, 0, 0, t3, 6), );
    PHASE(1, 1, 1, 0, 0, if (st) STAGE_H(1, 1, 0, t3, 5),
          if (st) { asm volatile("s_waitcnt vmcnt(4)" ::: "memory"); });
  }

  if (EPI == 0) {
#pragma unroll
    for (int fr = 0; fr < 8; ++fr) {
      long row0 = rowBase + wm * 128 + fr * 16 + lq * 4;
#pragma unroll
      for (int fc = 0; fc < 4; ++fc) {
        long col = colBase + wn * 64 + fc * 16 + l15;
#pragma unroll
        for (int j = 0; j < 4; ++j)
          Cf[(row0 + j) * 2048 + col] = acc[fr][fc][j];
      }
    }
  } else {
    const int sec = (int)(colBase >> 11);          // 0=q 1=k 2=v
#pragma unroll
    for (int fr = 0; fr < 8; ++fr) {
      int row0 = (int)rowBase + wm * 128 + fr * 16 + lq * 4;
      int b = row0 >> 11;
      int t0 = row0 & (T_ - 1);
#pragma unroll
      for (int fc = 0; fc < 4; ++fc) {
        int cc = (int)colBase + wn * 64 + fc * 16;
        int hh = (cc >> 7) & 15;
        int dd = (cc & 127) + l15;
        long bh = (long)b * H_ + hh;
        if (sec < 2) {
          u16* dst = sec ? kh : qh;
#pragma unroll
          for (int j = 0; j < 4; ++j) {
            float v = acc[fr][fc][j];
            float vp = __shfl_xor(v, 1);
            float2 cs = trig[(t0 + j) * 64 + (dd >> 1)];
            float r = (dd & 1) ? (vp * cs.y + v * cs.x) : (v * cs.x - vp * cs.y);
            dst[(bh * T_ + t0 + j) * 128 + dd] = f2bf(r);
          }
        } else {
          ushort4 pk;
          pk.x = f2bf(acc[fr][fc][0]); pk.y = f2bf(acc[fr][fc][1]);
          pk.z = f2bf(acc[fr][fc][2]); pk.w = f2bf(acc[fr][fc][3]);
          *reinterpret_cast<ushort4*>(&vt[(bh * 128 + dd) * T_ + t0]) = pk;
        }
      }
    }
  }
}

// pack 8 f32 P-values (S^T reg layout) into one PV A-fragment via cvt_pk + permlane32_swap
#define PACK_SLOT(dst, P, base)                                                       \
  {                                                                                   \
    unsigned ua, ub, uc, ud;                                                          \
    asm("v_cvt_pk_bf16_f32 %0, %1, %2" : "=v"(ua) : "v"(P[base + 0]), "v"(P[base + 1])); \
    asm("v_cvt_pk_bf16_f32 %0, %1, %2" : "=v"(ub) : "v"(P[base + 4]), "v"(P[base + 5])); \
    asm("v_permlane32_swap_b32 %0, %1" : "+v"(ua), "+v"(ub));                         \
    asm("v_cvt_pk_bf16_f32 %0, %1, %2" : "=v"(uc) : "v"(P[base + 2]), "v"(P[base + 3])); \
    asm("v_cvt_pk_bf16_f32 %0, %1, %2" : "=v"(ud) : "v"(P[base + 6]), "v"(P[base + 7])); \
    asm("v_permlane32_swap_b32 %0, %1" : "+v"(uc), "+v"(ud));                         \
    union { unsigned u[4]; bf16x8 v; } tt;                                            \
    tt.u[0] = ua; tt.u[1] = uc; tt.u[2] = ub; tt.u[3] = ud;                           \
    dst = tt.v;                                                                       \
  }

// flash attention, swapped-QK^T 32x32 structure.
__global__ __launch_bounds__(256, 2) void k_attn(
    const u16* __restrict__ qh, const u16* __restrict__ kh,
    const u16* __restrict__ vt, u16* __restrict__ ym) {
  __shared__ alignas(16) u16 lK[2][64 * 128];
  __shared__ alignas(16) u16 lV[2][128 * 64];
  const int tid = threadIdx.x;
  const int lane = tid & 63;
  const int w = tid >> 6;
  const int l31 = lane & 31;
  const int hi = lane >> 5;
  const int swz = (l31 & 7) << 4;
  const int id = (int)blockIdx.x;
  const int pr = id >> 6;
  const int bh = ((id & 7) << 3) | ((id >> 3) & 7);
  const int b = bh >> 4, hh = bh & 15;
  const u16* Kbase = kh + (long)bh * T_ * 128;
  const u16* Vbase = vt + (long)bh * 128 * T_;
  const u16* Qbase = qh + (long)bh * T_ * 128;

  auto stage = [&](int bi, int t0) {
#pragma unroll
    for (int i = 0; i < 4; ++i) {
      int c = tid + i * 256;
      int rK = c >> 4;
      int lbK = ((c & 15) << 4) ^ ((rK & 7) << 4);
      gld16(Kbase + (long)(t0 + rK) * 128 + (lbK >> 1), (char*)(&lK[bi][0]) + c * 16);
      int dV = c >> 3;
      int lbV = ((c & 7) << 4) ^ ((dV & 7) << 4);
      gld16(Vbase + (long)dV * T_ + t0 + (lbV >> 1), (char*)(&lV[bi][0]) + c * 16);
    }
  };

#pragma unroll 1
  for (int half = 0; half < 2; ++half) {
    const int p = half ? 15 - pr : pr;
    const int NT = 2 * (p + 1);
    const int qw = p * 128 + w * 32;
    const int ntw = (qw + 95) >> 6;

    bf16x8 qF[8];
    {
      const u16* qrow = Qbase + (long)(qw + l31) * 128 + hi * 8;
#pragma unroll
      for (int s = 0; s < 8; ++s)
        qF[s] = *reinterpret_cast<const bf16x8*>(qrow + s * 16);
    }

    f32x16 oA[4];
#pragma unroll
    for (int n = 0; n < 4; ++n)
#pragma unroll
      for (int r = 0; r < 16; ++r) oA[n][r] = 0.f;
    float mR = -1e30f, lR = 0.f;

    stage(0, 0);
    __syncthreads();
    int cur = 0;
#pragma unroll 1
    for (int jt = 0; jt < NT; ++jt) {
      if (jt + 1 < NT) stage(cur ^ 1, (jt + 1) * 64);
      if (jt < ntw) {
        const int t0 = jt * 64;
        const char* Kc = (const char*)(&lK[cur][0]);
        const char* Vc = (const char*)(&lV[cur][0]);
        f32x16 s0, s1;
#pragma unroll
        for (int r = 0; r < 16; ++r) { s0[r] = 0.f; s1[r] = 0.f; }
        __builtin_amdgcn_s_setprio(1);
#pragma unroll
        for (int s = 0; s < 8; ++s) {
          int cb = (s * 32 + hi * 16) ^ swz;
          bf16x8 k0 = *reinterpret_cast<const bf16x8*>(Kc + l31 * 256 + cb);
          bf16x8 k1 = *reinterpret_cast<const bf16x8*>(Kc + (32 + l31) * 256 + cb);
          s0 = __builtin_amdgcn_mfma_f32_32x32x16_bf16(k0, qF[s], s0, 0, 0, 0);
          s1 = __builtin_amdgcn_mfma_f32_32x32x16_bf16(k1, qF[s], s1, 0, 0, 0);
        }
        __builtin_amdgcn_s_setprio(0);

        float f0[16], f1[16];
#pragma unroll
        for (int r = 0; r < 16; ++r) { f0[r] = s0[r] * SCALE_; f1[r] = s1[r] * SCALE_; }
        if (jt == ntw - 1) {
          const int qa = qw + l31;
#pragma unroll
          for (int r = 0; r < 16; ++r) {
            int kv = t0 + (r & 3) + 8 * (r >> 2) + 4 * hi;
            if (kv > qa) f0[r] = -1e30f;
            if (kv + 32 > qa) f1[r] = -1e30f;
          }
        }
        float mt = fmaxf(f0[0], f1[0]);
#pragma unroll
        for (int r = 1; r < 16; ++r) mt = fmaxf(mt, fmaxf(f0[r], f1[r]));
        mt = fmaxf(mt, __shfl_xor(mt, 32));
        float mN = fmaxf(mR, mt);
        float al = __expf(mR - mN);
        mR = mN;
        float rs = 0.f;
#pragma unroll
        for (int r = 0; r < 16; ++r) {
          f0[r] = __expf(f0[r] - mN);
          f1[r] = __expf(f1[r] - mN);
          rs += f0[r] + f1[r];
        }
        rs += __shfl_xor(rs, 32);
        lR = lR * al + rs;
        float aR[16];
#pragma unroll
        for (int r = 0; r < 16; ++r)
          aR[r] = __shfl(al, (r & 3) + 8 * (r >> 2) + 4 * hi);
#pragma unroll
        for (int n = 0; n < 4; ++n)
#pragma unroll
          for (int r = 0; r < 16; ++r) oA[n][r] *= aR[r];

        bf16x8 paF[4];
        PACK_SLOT(paF[0], f0, 0);
        PACK_SLOT(paF[1], f0, 8);
        PACK_SLOT(paF[2], f1, 0);
        PACK_SLOT(paF[3], f1, 8);

        __builtin_amdgcn_s_setprio(1);
#pragma unroll
        for (int n = 0; n < 4; ++n) {
          const char* vrow = Vc + (n * 32 + l31) * 128;
#pragma unroll
          for (int ks = 0; ks < 4; ++ks) {
            bf16x8 bV = *reinterpret_cast<const bf16x8*>(vrow + ((ks * 32 + hi * 16) ^ swz));
            oA[n] = __builtin_amdgcn_mfma_f32_32x32x16_bf16(paF[ks], bV, oA[n], 0, 0, 0);
          }
        }
        __builtin_amdgcn_s_setprio(0);
      }
      __syncthreads();
      cur ^= 1;
    }

    float li = 1.f / lR;
    float liR[16];
#pragma unroll
    for (int r = 0; r < 16; ++r)
      liR[r] = __shfl(li, (r & 3) + 8 * (r >> 2) + 4 * hi);
    u16* yrow = ym + ((long)b * T_ + qw) * C_ + hh * 128 + l31;
#pragma unroll
    for (int n = 0; n < 4; ++n)
#pragma unroll
      for (int r = 0; r < 16; ++r) {
        int cr = (r & 3) + 8 * (r >> 2) + 4 * hi;
        yrow[(long)cr * C_ + n * 32] = f2bf(oA[n][r] * liR[r]);
      }
  }
}

extern "C" void kernel_launch(void* const* d_in, const int* in_sizes, int n_in,
                              void* d_out, int out_size, void* d_ws, size_t ws_size,
                              hipStream_t stream) {
  (void)in_sizes; (void)n_in; (void)out_size; (void)ws_size;
  const float* x = (const float*)d_in[0];
  const float* wa = (const float*)d_in[1];
  const float* wp = (const float*)d_in[2];
  float* out = (float*)d_out;
  char* ws = (char*)d_ws;

  size_t off = 0;
  auto alloc = [&](size_t bytes) -> char* {
    char* p = ws + off;
    off += (bytes + 255) & ~(size_t)255;
    return p;
  };
  u16* xb  = (u16*)alloc((size_t)M_ * C_ * 2);    // reused as ym after gemm1
  u16* wab = (u16*)alloc((size_t)N1_ * C_ * 2);
  u16* wpb = (u16*)alloc((size_t)C_ * C_ * 2);
  u16* qh  = (u16*)alloc((size_t)64 * T_ * 128 * 2);
  u16* kh  = (u16*)alloc((size_t)64 * T_ * 128 * 2);
  u16* vt  = (u16*)alloc((size_t)64 * 128 * T_ * 2);
  float2* trig = (float2*)alloc((size_t)T_ * 64 * 8);
  u16* ym = xb;

  k_cast<<<dim3((M_ * C_ / 4) / 256), 256, 0, stream>>>(x, xb, M_ * C_ / 4);
  k_cast<<<dim3((N1_ * C_ / 4) / 256), 256, 0, stream>>>(wa, wab, N1_ * C_ / 4);
  k_cast<<<dim3((C_ * C_ / 4) / 256), 256, 0, stream>>>(wp, wpb, C_ * C_ / 4);
  k_trig<<<dim3((T_ * 64) / 256), 256, 0, stream>>>(trig);
  // GEMM1: M=8192 N=6144 -> 32*24 = 768 blocks (nbx=24, cpx=96)
  k_gemm8<1><<<dim3(768), 512, 0, stream>>>(
      xb, wab, nullptr, qh, kh, vt, trig, 24, 96);
  k_attn<<<dim3(512), 256, 0, stream>>>(qh, kh, vt, ym);
  // GEMM2: M=8192 N=2048 -> 32*8 = 256 blocks (nbx=8, cpx=32)
  k_gemm8<0><<<dim3(256), 512, 0, stream>>>(
      ym, wpb, out, nullptr, nullptr, nullptr, nullptr, 8, 32);
}

// Round 5
// 408.424 us; speedup vs baseline: 1.7197x; 1.0140x over previous
//
#include <hip/hip_runtime.h>

#define B_ 4
#define T_ 2048
#define C_ 2048
#define H_ 16
#define N1_ 6144
#define M_ 8192
#define SCALE_ 0.08838834764831845f

typedef unsigned short u16;
typedef __bf16 bf16x8 __attribute__((ext_vector_type(8)));
typedef float f32x4 __attribute__((ext_vector_type(4)));
typedef float f32x16 __attribute__((ext_vector_type(16)));

__device__ __forceinline__ u16 f2bf(float f) {
  union { float f; unsigned u; } v; v.f = f;
  return (u16)((v.u + 0x7fffu + ((v.u >> 16) & 1u)) >> 16);
}
__device__ __forceinline__ float bf2f(u16 h) {
  union { unsigned u; float f; } v; v.u = ((unsigned)h) << 16;
  return v.f;
}

// async global->LDS, 16B per lane. LDS dest must be wave-uniform base + lane*16.
__device__ __forceinline__ void gld16(const void* g, void* l) {
  __builtin_amdgcn_global_load_lds(
      (__attribute__((address_space(1))) unsigned int*)(unsigned long long)g,
      (__attribute__((address_space(3))) unsigned int*)(unsigned)(unsigned long long)l,
      16, 0, 0);
}

__global__ void k_cast(const float* __restrict__ in, u16* __restrict__ out, int n4) {
  int i = blockIdx.x * 256 + threadIdx.x;
  if (i >= n4) return;
  float4 v = reinterpret_cast<const float4*>(in)[i];
  ushort4 o;
  o.x = f2bf(v.x); o.y = f2bf(v.y); o.z = f2bf(v.z); o.w = f2bf(v.w);
  reinterpret_cast<ushort4*>(out)[i] = o;
}

__global__ void k_trig(float2* __restrict__ trig) {
  int idx = blockIdx.x * 256 + threadIdx.x;   // T_*64 threads
  int t = idx >> 6, i = idx & 63;
  float theta = __expf(-(float)i * 0.14391156831212787f);
  float f = (float)t * theta;
  float s, c;
  sincosf(f, &s, &c);
  trig[idx] = make_float2(c, s);
}

// ---- 256x256 8-phase GEMM, single barrier per phase (wave-skew overlap) ----
// C[M][N] = A[M][2048] * Bt[N][2048]^T ; BM=BN=256 BK=64; 8 waves (2M x 4N);
// per-wave 128x64; 2 LDS buffers; 8 phases / 2 K-tiles; counted vmcnt(4) at
// phases 4,8; T2 XOR swizzle; T5 setprio. One s_barrier per phase at the TOP:
// a wave's reads(p+1)+stage(p+1) overlap its SIMD-mate's MFMA(p).
// Hazard audit (+-1 window skew): every half has >=2 windows between its read
// phase and restage phase; every read is >=1 barrier after the vmcnt that
// guarantees its stage landed (vmcnt(4)@P4 covers stages P8',P1,P2;
// vmcnt(4)@P8 covers P3..P6; tail vmcnt(0)@P4 when !st).

#define STAGE_H(BUF, AB, HALF, KT, GSH)                                          \
  {                                                                              \
    _Pragma("unroll") for (int q = 0; q < 2; ++q) {                              \
      int c = tid + q * 512;                                                     \
      int idx = c >> 3;                                                          \
      int row = (idx & ((1 << (GSH)) - 1)) + ((HALF) << (GSH)) +                 \
                ((idx >> (GSH)) << ((GSH) + 1));                                 \
      gld16(((AB) ? Bg : Ag) + (long)row * 2048 + (long)(KT) * 64 +              \
                (((c & 7) ^ (idx & 7)) << 3),                                    \
            (char*)&lds[BUF][AB][row * 64 + (c & 7) * 8]);                       \
    }                                                                            \
  }

#define PHASE(BUF, MH, NH, RDA, RDB, STAGE_CODE, WAIT_CODE)                      \
  {                                                                              \
    __builtin_amdgcn_s_barrier();                                                \
    __builtin_amdgcn_sched_barrier(0);                                           \
    if (RDA) {                                                                   \
      _Pragma("unroll") for (int fr = 0; fr < 4; ++fr)                           \
        _Pragma("unroll") for (int ks = 0; ks < 2; ++ks)                         \
          aCur[fr][ks] = *reinterpret_cast<const bf16x8*>(                       \
              &lds[BUF][0][(wm * 128 + (MH) * 64 + fr * 16 + l15) * 64 +         \
                           (((ks * 4 + lq) ^ swl) << 3)]);                       \
    }                                                                            \
    if (RDB) {                                                                   \
      _Pragma("unroll") for (int fc = 0; fc < 2; ++fc)                           \
        _Pragma("unroll") for (int ks = 0; ks < 2; ++ks)                         \
          bKp[NH][fc][ks] = *reinterpret_cast<const bf16x8*>(                    \
              &lds[BUF][1][(wn * 64 + (NH) * 32 + fc * 16 + l15) * 64 +          \
                           (((ks * 4 + lq) ^ swl) << 3)]);                       \
    }                                                                            \
    STAGE_CODE;                                                                  \
    __builtin_amdgcn_s_setprio(1);                                               \
    _Pragma("unroll") for (int fr = 0; fr < 4; ++fr)                             \
      _Pragma("unroll") for (int fc = 0; fc < 2; ++fc)                           \
        _Pragma("unroll") for (int ks = 0; ks < 2; ++ks)                         \
          acc[(MH) * 4 + fr][(NH) * 2 + fc] =                                    \
              __builtin_amdgcn_mfma_f32_16x16x32_bf16(                           \
                  aCur[fr][ks], bKp[NH][fc][ks],                                 \
                  acc[(MH) * 4 + fr][(NH) * 2 + fc], 0, 0, 0);                   \
    __builtin_amdgcn_s_setprio(0);                                               \
    WAIT_CODE;                                                                   \
  }

template <int EPI>
__global__ __launch_bounds__(512, 2) void k_gemm8(
    const u16* __restrict__ A, const u16* __restrict__ Bt,
    float* __restrict__ Cf,
    u16* __restrict__ qh, u16* __restrict__ kh, u16* __restrict__ vt,
    const float2* __restrict__ trig, int nbx, int cpx) {
  __shared__ alignas(16) u16 lds[2][2][256 * 64];
  const int tid = threadIdx.x;
  const int lane = tid & 63;
  const int w = tid >> 6;
  const int wm = w >> 2;          // 2 M-waves
  const int wn = w & 3;           // 4 N-waves
  const int l15 = lane & 15, lq = lane >> 4;
  const int swl = l15 & 7;

  const int id = (int)blockIdx.x;
  const int swz = (id & 7) * cpx + (id >> 3);   // bijective (grid % 8 == 0)
  const int bx = swz % nbx, by = swz / nbx;
  const long rowBase = (long)by * 256;
  const long colBase = (long)bx * 256;
  const u16* Ag = A + rowBase * 2048;
  const u16* Bg = Bt + colBase * 2048;

  const f32x4 z4 = {0.f, 0.f, 0.f, 0.f};
  f32x4 acc[8][4];
#pragma unroll
  for (int m = 0; m < 8; ++m)
#pragma unroll
    for (int n = 0; n < 4; ++n) acc[m][n] = z4;
  bf16x8 aCur[4][2], bKp[2][2][2];

  // prologue: tile0 -> buf0 (all 4 halves), tile1 -> buf1 halves A0,B0
  STAGE_H(0, 0, 0, 0, 6); STAGE_H(0, 1, 0, 0, 5);
  STAGE_H(0, 0, 1, 0, 6); STAGE_H(0, 1, 1, 0, 5);
  STAGE_H(1, 0, 0, 1, 6); STAGE_H(1, 1, 0, 1, 5);
  asm volatile("s_waitcnt vmcnt(4)" ::: "memory");

#pragma unroll 1
  for (int i = 0; i < 16; ++i) {
    const int t1 = 2 * i + 1, t2 = 2 * i + 2, t3 = 2 * i + 3;
    const bool st = (i < 15);
    PHASE(0, 0, 0, 1, 1, STAGE_H(1, 0, 1, t1, 6), );
    PHASE(0, 0, 1, 0, 1, STAGE_H(1, 1, 1, t1, 5), );
    PHASE(0, 1, 0, 1, 0, if (st) STAGE_H(0, 0, 0, t2, 6), );
    PHASE(0, 1, 1, 0, 0, if (st) STAGE_H(0, 1, 0, t2, 5),
          if (st) { asm volatile("s_waitcnt vmcnt(4)" ::: "memory"); }
          else    { asm volatile("s_waitcnt vmcnt(0)" ::: "memory"); });
    PHASE(1, 0, 0, 1, 1, if (st) STAGE_H(0, 0, 1, t2, 6), );
    PHASE(1, 0, 1, 0, 1, if (st) STAGE_H(0, 1, 1, t2, 5), );
    PHASE(1, 1, 0, 1, 0, if (st) STAGE_H(1, 0, 0, t3, 6), );
    PHASE(1, 1, 1, 0, 0, if (st) STAGE_H(1, 1, 0, t3, 5),
          if (st) { asm volatile("s_waitcnt vmcnt(4)" ::: "memory"); });
  }

  if (EPI == 0) {
#pragma unroll
    for (int fr = 0; fr < 8; ++fr) {
      long row0 = rowBase + wm * 128 + fr * 16 + lq * 4;
#pragma unroll
      for (int fc = 0; fc < 4; ++fc) {
        long col = colBase + wn * 64 + fc * 16 + l15;
#pragma unroll
        for (int j = 0; j < 4; ++j)
          Cf[(row0 + j) * 2048 + col] = acc[fr][fc][j];
      }
    }
  } else {
    const int sec = (int)(colBase >> 11);          // 0=q 1=k 2=v
#pragma unroll
    for (int fr = 0; fr < 8; ++fr) {
      int row0 = (int)rowBase + wm * 128 + fr * 16 + lq * 4;
      int b = row0 >> 11;
      int t0 = row0 & (T_ - 1);
#pragma unroll
      for (int fc = 0; fc < 4; ++fc) {
        int cc = (int)colBase + wn * 64 + fc * 16;
        int hh = (cc >> 7) & 15;
        int dd = (cc & 127) + l15;
        long bh = (long)b * H_ + hh;
        if (sec < 2) {
          u16* dst = sec ? kh : qh;
#pragma unroll
          for (int j = 0; j < 4; ++j) {
            float v = acc[fr][fc][j];
            float vp = __shfl_xor(v, 1);
            float2 cs = trig[(t0 + j) * 64 + (dd >> 1)];
            float r = (dd & 1) ? (vp * cs.y + v * cs.x) : (v * cs.x - vp * cs.y);
            dst[(bh * T_ + t0 + j) * 128 + dd] = f2bf(r);
          }
        } else {
          ushort4 pk;
          pk.x = f2bf(acc[fr][fc][0]); pk.y = f2bf(acc[fr][fc][1]);
          pk.z = f2bf(acc[fr][fc][2]); pk.w = f2bf(acc[fr][fc][3]);
          *reinterpret_cast<ushort4*>(&vt[(bh * 128 + dd) * T_ + t0]) = pk;
        }
      }
    }
  }
}

// pack 8 f32 P-values (S^T reg layout) into one PV A-fragment via cvt_pk + permlane32_swap
#define PACK_SLOT(dst, P, base)                                                       \
  {                                                                                   \
    unsigned ua, ub, uc, ud;                                                          \
    asm("v_cvt_pk_bf16_f32 %0, %1, %2" : "=v"(ua) : "v"(P[base + 0]), "v"(P[base + 1])); \
    asm("v_cvt_pk_bf16_f32 %0, %1, %2" : "=v"(ub) : "v"(P[base + 4]), "v"(P[base + 5])); \
    asm("v_permlane32_swap_b32 %0, %1" : "+v"(ua), "+v"(ub));                         \
    asm("v_cvt_pk_bf16_f32 %0, %1, %2" : "=v"(uc) : "v"(P[base + 2]), "v"(P[base + 3])); \
    asm("v_cvt_pk_bf16_f32 %0, %1, %2" : "=v"(ud) : "v"(P[base + 6]), "v"(P[base + 7])); \
    asm("v_permlane32_swap_b32 %0, %1" : "+v"(uc), "+v"(ud));                         \
    union { unsigned u[4]; bf16x8 v; } tt;                                            \
    tt.u[0] = ua; tt.u[1] = uc; tt.u[2] = ub; tt.u[3] = ud;                           \
    dst = tt.v;                                                                       \
  }

// flash attention, swapped-QK^T 32x32 structure.
__global__ __launch_bounds__(256, 2) void k_attn(
    const u16* __restrict__ qh, const u16* __restrict__ kh,
    const u16* __restrict__ vt, u16* __restrict__ ym) {
  __shared__ alignas(16) u16 lK[2][64 * 128];
  __shared__ alignas(16) u16 lV[2][128 * 64];
  const int tid = threadIdx.x;
  const int lane = tid & 63;
  const int w = tid >> 6;
  const int l31 = lane & 31;
  const int hi = lane >> 5;
  const int swz = (l31 & 7) << 4;
  const int id = (int)blockIdx.x;
  const int pr = id >> 6;
  const int bh = ((id & 7) << 3) | ((id >> 3) & 7);
  const int b = bh >> 4, hh = bh & 15;
  const u16* Kbase = kh + (long)bh * T_ * 128;
  const u16* Vbase = vt + (long)bh * 128 * T_;
  const u16* Qbase = qh + (long)bh * T_ * 128;

  auto stage = [&](int bi, int t0) {
#pragma unroll
    for (int i = 0; i < 4; ++i) {
      int c = tid + i * 256;
      int rK = c >> 4;
      int lbK = ((c & 15) << 4) ^ ((rK & 7) << 4);
      gld16(Kbase + (long)(t0 + rK) * 128 + (lbK >> 1), (char*)(&lK[bi][0]) + c * 16);
      int dV = c >> 3;
      int lbV = ((c & 7) << 4) ^ ((dV & 7) << 4);
      gld16(Vbase + (long)dV * T_ + t0 + (lbV >> 1), (char*)(&lV[bi][0]) + c * 16);
    }
  };

#pragma unroll 1
  for (int half = 0; half < 2; ++half) {
    const int p = half ? 15 - pr : pr;
    const int NT = 2 * (p + 1);
    const int qw = p * 128 + w * 32;
    const int ntw = (qw + 95) >> 6;

    bf16x8 qF[8];
    {
      const u16* qrow = Qbase + (long)(qw + l31) * 128 + hi * 8;
#pragma unroll
      for (int s = 0; s < 8; ++s)
        qF[s] = *reinterpret_cast<const bf16x8*>(qrow + s * 16);
    }

    f32x16 oA[4];
#pragma unroll
    for (int n = 0; n < 4; ++n)
#pragma unroll
      for (int r = 0; r < 16; ++r) oA[n][r] = 0.f;
    float mR = -1e30f, lR = 0.f;

    stage(0, 0);
    __syncthreads();
    int cur = 0;
#pragma unroll 1
    for (int jt = 0; jt < NT; ++jt) {
      if (jt + 1 < NT) stage(cur ^ 1, (jt + 1) * 64);
      if (jt < ntw) {
        const int t0 = jt * 64;
        const char* Kc = (const char*)(&lK[cur][0]);
        const char* Vc = (const char*)(&lV[cur][0]);
        f32x16 s0, s1;
#pragma unroll
        for (int r = 0; r < 16; ++r) { s0[r] = 0.f; s1[r] = 0.f; }
        __builtin_amdgcn_s_setprio(1);
#pragma unroll
        for (int s = 0; s < 8; ++s) {
          int cb = (s * 32 + hi * 16) ^ swz;
          bf16x8 k0 = *reinterpret_cast<const bf16x8*>(Kc + l31 * 256 + cb);
          bf16x8 k1 = *reinterpret_cast<const bf16x8*>(Kc + (32 + l31) * 256 + cb);
          s0 = __builtin_amdgcn_mfma_f32_32x32x16_bf16(k0, qF[s], s0, 0, 0, 0);
          s1 = __builtin_amdgcn_mfma_f32_32x32x16_bf16(k1, qF[s], s1, 0, 0, 0);
        }
        __builtin_amdgcn_s_setprio(0);

        float f0[16], f1[16];
#pragma unroll
        for (int r = 0; r < 16; ++r) { f0[r] = s0[r] * SCALE_; f1[r] = s1[r] * SCALE_; }
        if (jt == ntw - 1) {
          const int qa = qw + l31;
#pragma unroll
          for (int r = 0; r < 16; ++r) {
            int kv = t0 + (r & 3) + 8 * (r >> 2) + 4 * hi;
            if (kv > qa) f0[r] = -1e30f;
            if (kv + 32 > qa) f1[r] = -1e30f;
          }
        }
        float mt = fmaxf(f0[0], f1[0]);
#pragma unroll
        for (int r = 1; r < 16; ++r) mt = fmaxf(mt, fmaxf(f0[r], f1[r]));
        mt = fmaxf(mt, __shfl_xor(mt, 32));
        float mN = fmaxf(mR, mt);
        float al = __expf(mR - mN);
        mR = mN;
        float rs = 0.f;
#pragma unroll
        for (int r = 0; r < 16; ++r) {
          f0[r] = __expf(f0[r] - mN);
          f1[r] = __expf(f1[r] - mN);
          rs += f0[r] + f1[r];
        }
        rs += __shfl_xor(rs, 32);
        lR = lR * al + rs;
        float aR[16];
#pragma unroll
        for (int r = 0; r < 16; ++r)
          aR[r] = __shfl(al, (r & 3) + 8 * (r >> 2) + 4 * hi);
#pragma unroll
        for (int n = 0; n < 4; ++n)
#pragma unroll
          for (int r = 0; r < 16; ++r) oA[n][r] *= aR[r];

        bf16x8 paF[4];
        PACK_SLOT(paF[0], f0, 0);
        PACK_SLOT(paF[1], f0, 8);
        PACK_SLOT(paF[2], f1, 0);
        PACK_SLOT(paF[3], f1, 8);

        __builtin_amdgcn_s_setprio(1);
#pragma unroll
        for (int n = 0; n < 4; ++n) {
          const char* vrow = Vc + (n * 32 + l31) * 128;
#pragma unroll
          for (int ks = 0; ks < 4; ++ks) {
            bf16x8 bV = *reinterpret_cast<const bf16x8*>(vrow + ((ks * 32 + hi * 16) ^ swz));
            oA[n] = __builtin_amdgcn_mfma_f32_32x32x16_bf16(paF[ks], bV, oA[n], 0, 0, 0);
          }
        }
        __builtin_amdgcn_s_setprio(0);
      }
      __syncthreads();
      cur ^= 1;
    }

    float li = 1.f / lR;
    float liR[16];
#pragma unroll
    for (int r = 0; r < 16; ++r)
      liR[r] = __shfl(li, (r & 3) + 8 * (r >> 2) + 4 * hi);
    u16* yrow = ym + ((long)b * T_ + qw) * C_ + hh * 128 + l31;
#pragma unroll
    for (int n = 0; n < 4; ++n)
#pragma unroll
      for (int r = 0; r < 16; ++r) {
        int cr = (r & 3) + 8 * (r >> 2) + 4 * hi;
        yrow[(long)cr * C_ + n * 32] = f2bf(oA[n][r] * liR[r]);
      }
  }
}

extern "C" void kernel_launch(void* const* d_in, const int* in_sizes, int n_in,
                              void* d_out, int out_size, void* d_ws, size_t ws_size,
                              hipStream_t stream) {
  (void)in_sizes; (void)n_in; (void)out_size; (void)ws_size;
  const float* x = (const float*)d_in[0];
  const float* wa = (const float*)d_in[1];
  const float* wp = (const float*)d_in[2];
  float* out = (float*)d_out;
  char* ws = (char*)d_ws;

  size_t off = 0;
  auto alloc = [&](size_t bytes) -> char* {
    char* p = ws + off;
    off += (bytes + 255) & ~(size_t)255;
    return p;
  };
  u16* xb  = (u16*)alloc((size_t)M_ * C_ * 2);    // reused as ym after gemm1
  u16* wab = (u16*)alloc((size_t)N1_ * C_ * 2);
  u16* wpb = (u16*)alloc((size_t)C_ * C_ * 2);
  u16* qh  = (u16*)alloc((size_t)64 * T_ * 128 * 2);
  u16* kh  = (u16*)alloc((size_t)64 * T_ * 128 * 2);
  u16* vt  = (u16*)alloc((size_t)64 * 128 * T_ * 2);
  float2* trig = (float2*)alloc((size_t)T_ * 64 * 8);
  u16* ym = xb;

  k_cast<<<dim3((M_ * C_ / 4) / 256), 256, 0, stream>>>(x, xb, M_ * C_ / 4);
  k_cast<<<dim3((N1_ * C_ / 4) / 256), 256, 0, stream>>>(wa, wab, N1_ * C_ / 4);
  k_cast<<<dim3((C_ * C_ / 4) / 256), 256, 0, stream>>>(wp, wpb, C_ * C_ / 4);
  k_trig<<<dim3((T_ * 64) / 256), 256, 0, stream>>>(trig);
  // GEMM1: M=8192 N=6144 -> 32*24 = 768 blocks (nbx=24, cpx=96)
  k_gemm8<1><<<dim3(768), 512, 0, stream>>>(
      xb, wab, nullptr, qh, kh, vt, trig, 24, 96);
  k_attn<<<dim3(512), 256, 0, stream>>>(qh, kh, vt, ym);
  // GEMM2: M=8192 N=2048 -> 32*8 = 256 blocks (nbx=8, cpx=32)
  k_gemm8<0><<<dim3(256), 512, 0, stream>>>(
      ym, wpb, out, nullptr, nullptr, nullptr, nullptr, 8, 32);
}